// Round 1
// baseline (357.450 us; speedup 1.0000x reference)
//
#include <hip/hip_runtime.h>
#include <hip/hip_bf16.h>
#include <stdint.h>

#define B_ROWS 8192
#define N_TOT  16384
#define D_DIM  128
#define INV_TEMP (1.0f / 0.07f)

typedef __bf16 bf16x8 __attribute__((ext_vector_type(8)));
typedef float  f32x4  __attribute__((ext_vector_type(4)));

// ---------------- Kernel 1: normalize rows of concat(q,k) -> bf16 ----------
// One wave (64 lanes) per row, 2 floats per lane (float2). Packed bf16x2 out.
__global__ void simclr_norm_kernel(const float* __restrict__ q,
                                   const float* __restrict__ k,
                                   unsigned int* __restrict__ fb) {
    const int lane = threadIdx.x & 63;
    const int row  = blockIdx.x * 4 + (threadIdx.x >> 6);
    const float* src = (row < B_ROWS) ? (q + (size_t)row * D_DIM)
                                      : (k + (size_t)(row - B_ROWS) * D_DIM);
    float2 v = ((const float2*)src)[lane];
    float s = v.x * v.x + v.y * v.y;
#pragma unroll
    for (int off = 32; off > 0; off >>= 1) s += __shfl_xor(s, off);
    float rn = 1.0f / fmaxf(sqrtf(s), 1e-12f);
    union { __bf16 h[2]; unsigned int u; } pk;
    pk.h[0] = (__bf16)(v.x * rn);
    pk.h[1] = (__bf16)(v.y * rn);
    fb[(size_t)row * 64 + lane] = pk.u;
}

// ---------------- Kernel 2: sim = f f^T (bf16 MFMA) + fused permute/scale ---
// 128x128 output tile per block, full K=128 staged in LDS (64 KiB).
// Staging: global_load_lds width=16, source pre-swizzled (chunk ^= row&7) so
// the fragment ds_read_b128 (XOR-swizzled address) is bank-conflict-free.
__global__ __launch_bounds__(256, 2) void simclr_gemm_kernel(
        const unsigned short* __restrict__ fb, float* __restrict__ out) {
    __shared__ char lds[65536];  // A tile [0,32768), B tile [32768,65536)

    const int brow = blockIdx.x >> 7;
    const int bcol = blockIdx.x & 127;
    const int tid  = threadIdx.x;
    const int lane = tid & 63;
    const int w    = tid >> 6;       // wave id 0..3

    // ---- stage A and B tiles (each 128 rows x 128 bf16 = 32 KiB) ----
    {
        const int chunk = lane & 15;   // 16B chunk within a 256B row
        const int rsub  = lane >> 4;   // row within the 4-row group
#pragma unroll
        for (int i = 0; i < 8; ++i) {
            const int r = w * 32 + i * 4 + rsub;        // local row 0..127
            const int src_chunk = chunk ^ (r & 7);      // pre-swizzle source
            const char* gA = (const char*)(fb + ((size_t)(brow * 128 + r) * D_DIM + src_chunk * 8));
            const char* gB = (const char*)(fb + ((size_t)(bcol * 128 + r) * D_DIM + src_chunk * 8));
            char* lA = lds + (w * 32 + i * 4) * 256;
            char* lB = lds + 32768 + (w * 32 + i * 4) * 256;
            __builtin_amdgcn_global_load_lds((const __attribute__((address_space(1))) void*)gA,
                                             (__attribute__((address_space(3))) void*)lA, 16, 0, 0);
            __builtin_amdgcn_global_load_lds((const __attribute__((address_space(1))) void*)gB,
                                             (__attribute__((address_space(3))) void*)lB, 16, 0, 0);
        }
    }
    __syncthreads();

    // ---- MFMA compute: each wave computes a 64x64 sub-tile ----
    const int wr = w >> 1, wc = w & 1;
    const int rl = lane & 15;   // row-in-frag (A) / col-in-frag (B)
    const int kg = lane >> 4;   // k-group

    f32x4 acc[4][4];
#pragma unroll
    for (int m = 0; m < 4; ++m)
#pragma unroll
        for (int n = 0; n < 4; ++n) acc[m][n] = (f32x4){0.f, 0.f, 0.f, 0.f};

#pragma unroll
    for (int ks = 0; ks < 4; ++ks) {
        bf16x8 afr[4], bfr[4];
        const int kb = ks * 64 + kg * 16;
#pragma unroll
        for (int m = 0; m < 4; ++m) {
            const int r = wr * 64 + m * 16 + rl;
            afr[m] = *(const bf16x8*)(lds + r * 256 + (kb ^ ((r & 7) << 4)));
        }
#pragma unroll
        for (int n = 0; n < 4; ++n) {
            const int r = wc * 64 + n * 16 + rl;
            bfr[n] = *(const bf16x8*)(lds + 32768 + r * 256 + (kb ^ ((r & 7) << 4)));
        }
#pragma unroll
        for (int m = 0; m < 4; ++m)
#pragma unroll
            for (int n = 0; n < 4; ++n)
                acc[m][n] = __builtin_amdgcn_mfma_f32_16x16x32_bf16(afr[m], bfr[n], acc[m][n], 0, 0, 0);
    }

    // ---- fused epilogue: permute columns, scale by 1/TEMP, store ----
    // C/D layout (16x16x32): col = lane&15, row = (lane>>4)*4 + reg.
    const int i0 = brow * 128 + wr * 64 + (kg << 2);
    const int c0 = bcol * 128 + wc * 64 + rl;
#pragma unroll
    for (int m = 0; m < 4; ++m) {
#pragma unroll
        for (int r = 0; r < 4; ++r) {
            const int i = i0 + m * 16 + r;
            const int p = i ^ B_ROWS;          // positive-pair index
            const int a = i & (B_ROWS - 1);    // min(i,p)
            const int b = a | B_ROWS;          // max(i,p)
            float* orow = out + (size_t)i * (N_TOT - 1);
#pragma unroll
            for (int n = 0; n < 4; ++n) {
                const int c = c0 + n * 16;
                const float v = acc[m][n][r] * INV_TEMP;
                if (c == i) continue;          // diagonal: dropped
                const int col = (c == p) ? 0 : (c + 1 - (c > a) - (c > b));
                orow[col] = v;
            }
        }
    }
}

// ---------------- Kernel 3: labels = zeros (int32 0 == fp32 0.0 bits) ------
__global__ void simclr_zero_labels(float* __restrict__ out) {
    out[(size_t)N_TOT * (N_TOT - 1) + blockIdx.x * 256 + threadIdx.x] = 0.0f;
}

extern "C" void kernel_launch(void* const* d_in, const int* in_sizes, int n_in,
                              void* d_out, int out_size, void* d_ws, size_t ws_size,
                              hipStream_t stream) {
    const float* q = (const float*)d_in[0];
    const float* k = (const float*)d_in[1];
    float* out = (float*)d_out;
    unsigned int* fb = (unsigned int*)d_ws;   // 16384*128 bf16 = 4 MiB scratch

    simclr_norm_kernel<<<N_TOT / 4, 256, 0, stream>>>(q, k, fb);
    simclr_zero_labels<<<N_TOT / 256, 256, 0, stream>>>(out);
    simclr_gemm_kernel<<<128 * 128, 256, 0, stream>>>((const unsigned short*)d_ws, out);
}